// Round 2
// baseline (1394.157 us; speedup 1.0000x reference)
//
#include <hip/hip_runtime.h>
#include <stdint.h>

typedef __bf16 bf16x8 __attribute__((ext_vector_type(8)));
typedef float f32x4 __attribute__((ext_vector_type(4)));

#define NSTEP 10
#define HALF_V 16777216u  /* 4096*4096: pair offset for (8192,4096) uniforms */
#define HALF_H 262144u    /* 4096*64:   pair offset for (8192,64)   uniforms */

struct TFKeys {
  uint32_t kh0_0, kh0_1;                 // fold_in(key(42), 0) — initial h sample
  uint32_t kv0[NSTEP], kv1[NSTEP];       // per-step v keys
  uint32_t khs0[NSTEP], khs1[NSTEP];     // per-step h keys
};

#define TF_ROUND(r) { x0 += x1; x1 = (x1 << (r)) | (x1 >> (32 - (r))); x1 ^= x0; }

__host__ __device__ __forceinline__ void tf2x32(uint32_t k0, uint32_t k1,
    uint32_t x0, uint32_t x1, uint32_t& o0, uint32_t& o1) {
  const uint32_t k2 = k0 ^ k1 ^ 0x1BD11BDAu;
  x0 += k0; x1 += k1;
  TF_ROUND(13) TF_ROUND(15) TF_ROUND(26) TF_ROUND(6)
  x0 += k1; x1 += k2 + 1u;
  TF_ROUND(17) TF_ROUND(29) TF_ROUND(16) TF_ROUND(24)
  x0 += k2; x1 += k0 + 2u;
  TF_ROUND(13) TF_ROUND(15) TF_ROUND(26) TF_ROUND(6)
  x0 += k0; x1 += k1 + 3u;
  TF_ROUND(17) TF_ROUND(29) TF_ROUND(16) TF_ROUND(24)
  x0 += k1; x1 += k2 + 4u;
  TF_ROUND(13) TF_ROUND(15) TF_ROUND(26) TF_ROUND(6)
  x0 += k2; x1 += k0 + 5u;
  o0 = x0; o1 = x1;
}

__device__ __forceinline__ float tf_uniform(uint32_t bits) {
  return __uint_as_float((bits >> 9) | 0x3F800000u) - 1.0f;   // [0,1) like JAX
}

__device__ __forceinline__ float sigmoidf_(float x) {
  return 1.0f / (1.0f + __expf(-x));
}

__device__ __forceinline__ float softplusf_(float x) {
  return fmaxf(x, 0.0f) + log1pf(__expf(-fabsf(x)));
}

__device__ __forceinline__ unsigned short f2bf(float f) {
  uint32_t u = __float_as_uint(f);
  uint32_t r = (u + 0x7FFFu + ((u >> 16) & 1u)) >> 16;  // RNE
  return (unsigned short)r;
}

__device__ __forceinline__ bf16x8 as8(uint4 u) { return __builtin_bit_cast(bf16x8, u); }

// ---- prep: w (f32 [4096,64]) -> split bf16 (hi+lo) row-major + transposed ----
__global__ void prep_w(const float* __restrict__ w,
                       unsigned short* __restrict__ w_hi, unsigned short* __restrict__ w_lo,
                       unsigned short* __restrict__ wt_hi, unsigned short* __restrict__ wt_lo) {
  int t = blockIdx.x * 256 + threadIdx.x;   // 262144 total
  int i = t >> 6, j = t & 63;
  float f = w[t];
  unsigned short hi = f2bf(f);
  float fh = __uint_as_float((uint32_t)hi << 16);
  unsigned short lo = f2bf(f - fh);
  w_hi[t] = hi;            w_lo[t] = lo;
  wt_hi[j * 4096 + i] = hi; wt_lo[j * 4096 + i] = lo;
}

// ---- fused CD-10 chain + free energy, one block per 16 paired rows (32 rows) ----
__global__ __launch_bounds__(512, 2)
void rbm_chain(const float* __restrict__ inputs, const float* __restrict__ vb,
               const float* __restrict__ hb,
               const unsigned short* __restrict__ w_hi, const unsigned short* __restrict__ w_lo,
               const unsigned short* __restrict__ wt_hi, const unsigned short* __restrict__ wt_lo,
               float* __restrict__ partial, TFKeys K) {
  __shared__ unsigned short v_lds[32][520];  // chunk of v (or staged inputs) as bf16
  __shared__ unsigned short h_lds[32][72];   // h as bf16
  __shared__ float vb_lds[4096];
  __shared__ float hb_lds[64];
  __shared__ float red[8];

  const int tid = threadIdx.x;
  const int wv  = tid >> 6;    // wave 0..7
  const int l   = tid & 63;
  const int lg  = l >> 4;      // 0..3 (K-group / acc row-group)
  const int lr  = l & 15;
  const int b0  = blockIdx.x * 16;
  const int rt  = wv >> 2;     // row-tile for X-accumulate (0/1)
  const int cth = wv & 3;      // hidden col-tile (16 cols each)
  const int j   = cth * 16 + lr;            // hidden index owned in X epilogues
  const size_t wtrow = (size_t)j * 4096;    // row of wt_hi/wt_lo this lane reads

  for (int u = tid; u < 1024; u += 512)
    ((float4*)vb_lds)[u] = ((const float4*)vb)[u];
  if (tid < 64) hb_lds[tid] = hb[tid];
  __syncthreads();

  float acc_fe = 0.0f;

  // ================= X0 = inputs @ w : bias_in, cond_in, sample h0 ==========
  {
    f32x4 accx = {0.f, 0.f, 0.f, 0.f};
    for (int c = 0; c < 8; ++c) {
      { // stage inputs chunk -> bf16 in v_lds; accumulate -inputs.vb
        const int row  = tid >> 4;  // 0..31
        const int grow = (row < 16) ? (b0 + row) : (4096 + b0 + (row - 16));
        const float4* src = (const float4*)(inputs + (size_t)grow * 4096 + c * 512);
        #pragma unroll
        for (int uu = 0; uu < 8; ++uu) {
          int f = (tid & 15) + (uu << 4);      // float4 index in [0,128)
          float4 x = src[f];
          int cg = c * 512 + 4 * f;
          acc_fe -= x.x * vb_lds[cg] + x.y * vb_lds[cg + 1]
                  + x.z * vb_lds[cg + 2] + x.w * vb_lds[cg + 3];
          ushort4 h4;
          h4.x = f2bf(x.x); h4.y = f2bf(x.y); h4.z = f2bf(x.z); h4.w = f2bf(x.w);
          *(ushort4*)&v_lds[row][4 * f] = h4;
        }
      }
      __syncthreads();
      #pragma unroll
      for (int ks = 0; ks < 16; ++ks) {
        bf16x8 a  = as8(*(const uint4*)&v_lds[rt * 16 + lr][ks * 32 + lg * 8]);
        bf16x8 bh = as8(*(const uint4*)(wt_hi + wtrow + c * 512 + ks * 32 + lg * 8));
        bf16x8 bl = as8(*(const uint4*)(wt_lo + wtrow + c * 512 + ks * 32 + lg * 8));
        accx = __builtin_amdgcn_mfma_f32_16x16x32_bf16(a, bh, accx, 0, 0, 0);
        accx = __builtin_amdgcn_mfma_f32_16x16x32_bf16(a, bl, accx, 0, 0, 0);
      }
      __syncthreads();
    }
    // epilogue: cond_in softplus + h0 sample
    float hbv = hb_lds[j];
    #pragma unroll
    for (int q = 0; q < 4; ++q) {
      float x = accx[q] + hbv;
      acc_fe -= softplusf_(x);
      int rit = lg * 4 + q;
      uint32_t e0 = (uint32_t)(b0 + rit) * 64u + (uint32_t)j;
      uint32_t o0, o1;
      tf2x32(K.kh0_0, K.kh0_1, e0, e0 + HALF_H, o0, o1);
      float u = tf_uniform(rt ? o1 : o0);
      h_lds[rt * 16 + rit][j] = (sigmoidf_(x) > u) ? (unsigned short)0x3F80 : (unsigned short)0;
    }
  }

  // ======================= 10 Gibbs steps ===================================
  for (int step = 0; step < NSTEP; ++step) {
    const uint32_t kv0 = K.kv0[step], kv1 = K.kv1[step];
    const uint32_t kh0 = K.khs0[step], kh1 = K.khs1[step];
    const bool last = (step == NSTEP - 1);
    __syncthreads();  // h_lds ready

    // A-fragments of H for both row-tiles (K=64 -> 2 k-steps each)
    bf16x8 ha00 = as8(*(const uint4*)&h_lds[lr][lg * 8]);
    bf16x8 ha01 = as8(*(const uint4*)&h_lds[lr][32 + lg * 8]);
    bf16x8 ha10 = as8(*(const uint4*)&h_lds[16 + lr][lg * 8]);
    bf16x8 ha11 = as8(*(const uint4*)&h_lds[16 + lr][32 + lg * 8]);

    f32x4 accx = {0.f, 0.f, 0.f, 0.f};

    for (int c = 0; c < 8; ++c) {
      // ---- v-phase: P = H @ W^T on 4 col-tiles/wave, sample v -> v_lds ----
      #pragma unroll
      for (int k = 0; k < 4; ++k) {
        int ctl = wv + 8 * k;                 // chunk-local col-tile 0..31
        int ig  = (c * 32 + ctl) * 16 + lr;   // global visible index
        const uint4* wh = (const uint4*)(w_hi + (size_t)ig * 64);
        const uint4* wl = (const uint4*)(w_lo + (size_t)ig * 64);
        bf16x8 bh0 = as8(wh[lg]);       // W[ig][k: 0..31]  (hi)
        bf16x8 bh1 = as8(wh[4 + lg]);   // W[ig][k:32..63]  (hi)
        bf16x8 bl0 = as8(wl[lg]);
        bf16x8 bl1 = as8(wl[4 + lg]);
        f32x4 a0 = {0.f, 0.f, 0.f, 0.f}, a1 = {0.f, 0.f, 0.f, 0.f};
        a0 = __builtin_amdgcn_mfma_f32_16x16x32_bf16(ha00, bh0, a0, 0, 0, 0);
        a0 = __builtin_amdgcn_mfma_f32_16x16x32_bf16(ha01, bh1, a0, 0, 0, 0);
        a0 = __builtin_amdgcn_mfma_f32_16x16x32_bf16(ha00, bl0, a0, 0, 0, 0);
        a0 = __builtin_amdgcn_mfma_f32_16x16x32_bf16(ha01, bl1, a0, 0, 0, 0);
        a1 = __builtin_amdgcn_mfma_f32_16x16x32_bf16(ha10, bh0, a1, 0, 0, 0);
        a1 = __builtin_amdgcn_mfma_f32_16x16x32_bf16(ha11, bh1, a1, 0, 0, 0);
        a1 = __builtin_amdgcn_mfma_f32_16x16x32_bf16(ha10, bl0, a1, 0, 0, 0);
        a1 = __builtin_amdgcn_mfma_f32_16x16x32_bf16(ha11, bl1, a1, 0, 0, 0);
        float vbv = vb_lds[ig];
        #pragma unroll
        for (int q = 0; q < 4; ++q) {
          int rit = lg * 4 + q;
          float x0 = a0[q] + vbv, x1 = a1[q] + vbv;
          uint32_t e0 = (uint32_t)(b0 + rit) * 4096u + (uint32_t)ig;
          uint32_t o0, o1;
          tf2x32(kv0, kv1, e0, e0 + HALF_V, o0, o1);
          bool s0 = sigmoidf_(x0) > tf_uniform(o0);
          bool s1 = sigmoidf_(x1) > tf_uniform(o1);
          v_lds[rit][ctl * 16 + lr]      = s0 ? (unsigned short)0x3F80 : (unsigned short)0;
          v_lds[16 + rit][ctl * 16 + lr] = s1 ? (unsigned short)0x3F80 : (unsigned short)0;
          if (last) acc_fe += (s0 ? vbv : 0.0f) + (s1 ? vbv : 0.0f);  // + v.vb
        }
      }
      __syncthreads();
      // ---- h-phase partial: X += Vchunk @ W (hi + lo passes) ----
      #pragma unroll
      for (int ks = 0; ks < 16; ++ks) {
        bf16x8 a  = as8(*(const uint4*)&v_lds[rt * 16 + lr][ks * 32 + lg * 8]);
        bf16x8 bh = as8(*(const uint4*)(wt_hi + wtrow + c * 512 + ks * 32 + lg * 8));
        bf16x8 bl = as8(*(const uint4*)(wt_lo + wtrow + c * 512 + ks * 32 + lg * 8));
        accx = __builtin_amdgcn_mfma_f32_16x16x32_bf16(a, bh, accx, 0, 0, 0);
        accx = __builtin_amdgcn_mfma_f32_16x16x32_bf16(a, bl, accx, 0, 0, 0);
      }
      __syncthreads();
    }

    // ---- epilogue: sample h (steps 0..8) or cond_v softplus (step 9) ----
    float hbv = hb_lds[j];
    #pragma unroll
    for (int q = 0; q < 4; ++q) {
      float x = accx[q] + hbv;
      int rit = lg * 4 + q;
      if (last) {
        acc_fe += softplusf_(x);
      } else {
        uint32_t e0 = (uint32_t)(b0 + rit) * 64u + (uint32_t)j;
        uint32_t o0, o1;
        tf2x32(kh0, kh1, e0, e0 + HALF_H, o0, o1);
        float u = tf_uniform(rt ? o1 : o0);
        h_lds[rt * 16 + rit][j] = (sigmoidf_(x) > u) ? (unsigned short)0x3F80 : (unsigned short)0;
      }
    }
  }

  // ---- block reduction ----
  float v = acc_fe;
  #pragma unroll
  for (int off = 32; off; off >>= 1) v += __shfl_down(v, off);
  if (l == 0) red[wv] = v;
  __syncthreads();
  if (tid == 0) {
    float s = 0.f;
    #pragma unroll
    for (int i = 0; i < 8; ++i) s += red[i];
    partial[blockIdx.x] = s;
  }
}

__global__ void finish_reduce(const float* __restrict__ partial, float* __restrict__ out) {
  __shared__ float r[4];
  float v = partial[threadIdx.x];   // 256 threads
  #pragma unroll
  for (int off = 32; off; off >>= 1) v += __shfl_down(v, off);
  if ((threadIdx.x & 63) == 0) r[threadIdx.x >> 6] = v;
  __syncthreads();
  if (threadIdx.x == 0) out[0] = r[0] + r[1] + r[2] + r[3];
}

extern "C" void kernel_launch(void* const* d_in, const int* in_sizes, int n_in,
                              void* d_out, int out_size, void* d_ws, size_t ws_size,
                              hipStream_t stream) {
  const float* inputs = (const float*)d_in[0];
  const float* w      = (const float*)d_in[1];
  const float* vb     = (const float*)d_in[2];
  const float* hb     = (const float*)d_in[3];
  float* out = (float*)d_out;

  unsigned short* w_hi  = (unsigned short*)d_ws;                          // 512 KB
  unsigned short* w_lo  = (unsigned short*)((char*)d_ws + (512u << 10));  // 512 KB
  unsigned short* wt_hi = (unsigned short*)((char*)d_ws + (1024u << 10)); // 512 KB
  unsigned short* wt_lo = (unsigned short*)((char*)d_ws + (1536u << 10)); // 512 KB
  float* partial        = (float*)((char*)d_ws + (2048u << 10));

  // ---- JAX threefry key schedule on host (pure arithmetic, capture-safe) ----
  TFKeys K;
  uint32_t kc0, kc1;
  tf2x32(0u, 42u, 0u, 0u, K.kh0_0, K.kh0_1);   // fold_in(key(42), 0)
  tf2x32(0u, 42u, 0u, 1u, kc0, kc1);           // fold_in(key(42), 1)
  // split(kchain, 10): counts = iota(20), cipher pairs (i, 10+i)
  uint32_t A[NSTEP], B[NSTEP], flat[2 * NSTEP];
  for (int i = 0; i < NSTEP; ++i) tf2x32(kc0, kc1, (uint32_t)i, (uint32_t)(NSTEP + i), A[i], B[i]);
  for (int i = 0; i < NSTEP; ++i) { flat[i] = A[i]; flat[NSTEP + i] = B[i]; }
  for (int t = 0; t < NSTEP; ++t) {
    uint32_t key0 = flat[2 * t], key1 = flat[2 * t + 1];
    // split(keys[t], 2): counts = iota(4), cipher pairs (0,2) and (1,3)
    uint32_t C0, D0, C1, D1;
    tf2x32(key0, key1, 0u, 2u, C0, D0);
    tf2x32(key0, key1, 1u, 3u, C1, D1);
    K.kv0[t] = C0; K.kv1[t] = C1;    // kv = first row of reshaped (2,2)
    K.khs0[t] = D0; K.khs1[t] = D1;  // kh = second row
  }

  prep_w<<<1024, 256, 0, stream>>>(w, w_hi, w_lo, wt_hi, wt_lo);
  rbm_chain<<<256, 512, 0, stream>>>(inputs, vb, hb, w_hi, w_lo, wt_hi, wt_lo, partial, K);
  finish_reduce<<<1, 256, 0, stream>>>(partial, out);
}

// Round 3
// 905.851 us; speedup vs baseline: 1.5391x; 1.5391x over previous
//
#include <hip/hip_runtime.h>
#include <stdint.h>

typedef __bf16 bf16x8 __attribute__((ext_vector_type(8)));
typedef float f32x4 __attribute__((ext_vector_type(4)));

#define NSTEP 10
#define HALF_V 16777216u  /* 4096*4096: pair offset for (8192,4096) uniforms */
#define HALF_H 262144u    /* 4096*64:   pair offset for (8192,64)   uniforms */

struct TFKeys {
  uint32_t kh0_0, kh0_1;                 // fold_in(key(42), 0) — initial h sample
  uint32_t kv0[NSTEP], kv1[NSTEP];       // per-step v keys
  uint32_t khs0[NSTEP], khs1[NSTEP];     // per-step h keys
};

#define TF_ROUND(r) { x0 += x1; x1 = (x1 << (r)) | (x1 >> (32 - (r))); x1 ^= x0; }

__host__ __device__ __forceinline__ void tf2x32(uint32_t k0, uint32_t k1,
    uint32_t x0, uint32_t x1, uint32_t& o0, uint32_t& o1) {
  const uint32_t k2 = k0 ^ k1 ^ 0x1BD11BDAu;
  x0 += k0; x1 += k1;
  TF_ROUND(13) TF_ROUND(15) TF_ROUND(26) TF_ROUND(6)
  x0 += k1; x1 += k2 + 1u;
  TF_ROUND(17) TF_ROUND(29) TF_ROUND(16) TF_ROUND(24)
  x0 += k2; x1 += k0 + 2u;
  TF_ROUND(13) TF_ROUND(15) TF_ROUND(26) TF_ROUND(6)
  x0 += k0; x1 += k1 + 3u;
  TF_ROUND(17) TF_ROUND(29) TF_ROUND(16) TF_ROUND(24)
  x0 += k1; x1 += k2 + 4u;
  TF_ROUND(13) TF_ROUND(15) TF_ROUND(26) TF_ROUND(6)
  x0 += k2; x1 += k0 + 5u;
  o0 = x0; o1 = x1;
}

__device__ __forceinline__ float tf_uniform(uint32_t bits) {
  return __uint_as_float((bits >> 9) | 0x3F800000u) - 1.0f;   // [0,1) like JAX
}

__device__ __forceinline__ float sigmoidf_(float x) {
  return 1.0f / (1.0f + __expf(-x));
}

__device__ __forceinline__ float softplusf_(float x) {
  return fmaxf(x, 0.0f) + log1pf(__expf(-fabsf(x)));
}

__device__ __forceinline__ unsigned short f2bf(float f) {
  uint32_t u = __float_as_uint(f);
  uint32_t r = (u + 0x7FFFu + ((u >> 16) & 1u)) >> 16;  // RNE
  return (unsigned short)r;
}

__device__ __forceinline__ bf16x8 as8(uint4 u) { return __builtin_bit_cast(bf16x8, u); }

// ---- prep: w (f32 [4096,64]) -> split bf16 (hi+lo) row-major + transposed ----
__global__ void prep_w(const float* __restrict__ w,
                       unsigned short* __restrict__ w_hi, unsigned short* __restrict__ w_lo,
                       unsigned short* __restrict__ wt_hi, unsigned short* __restrict__ wt_lo) {
  int t = blockIdx.x * 256 + threadIdx.x;   // 262144 total
  int i = t >> 6, j = t & 63;
  float f = w[t];
  unsigned short hi = f2bf(f);
  float fh = __uint_as_float((uint32_t)hi << 16);
  unsigned short lo = f2bf(f - fh);
  w_hi[t] = hi;             w_lo[t] = lo;
  wt_hi[j * 4096 + i] = hi; wt_lo[j * 4096 + i] = lo;
}

// ---- h-sampling / free-energy tail: 1024 ciphers per block, 2 per lane ----
// MODE 0: X0 phase  (acc_fe -= softplus, sample h)
// MODE 1: mid step  (sample h only)
// MODE 2: last step (acc_fe += softplus, no sample)
template<int MODE>
__device__ __forceinline__ void h_tail(int wv, int l, int b0, uint32_t k0, uint32_t k1,
    float& acc_fe, const float (*Xp)[64][8], const float* hb_lds,
    unsigned short (*h_lds)[72]) {
  const int cc  = (wv * 64 + l) * 2;
  const int rlo = cc >> 6;          // 0..15
  const int j0  = cc & 63;          // even
  #pragma unroll
  for (int s = 0; s < 2; ++s) {
    const int jj = j0 + s;
    f32x4 pa = *(const f32x4*)&Xp[rlo][jj][0];
    f32x4 pb = *(const f32x4*)&Xp[rlo][jj][4];
    f32x4 qa = *(const f32x4*)&Xp[rlo + 16][jj][0];
    f32x4 qb = *(const f32x4*)&Xp[rlo + 16][jj][4];
    float hbv = hb_lds[jj];
    float xlo = (((pa[0] + pa[1]) + (pa[2] + pa[3]))
               + ((pb[0] + pb[1]) + (pb[2] + pb[3]))) + hbv;
    float xhi = (((qa[0] + qa[1]) + (qa[2] + qa[3]))
               + ((qb[0] + qb[1]) + (qb[2] + qb[3]))) + hbv;
    if (MODE == 2) {
      acc_fe += softplusf_(xlo) + softplusf_(xhi);
    } else {
      if (MODE == 0) acc_fe -= softplusf_(xlo) + softplusf_(xhi);
      uint32_t e0 = (uint32_t)(b0 + rlo) * 64u + (uint32_t)jj;
      uint32_t o0, o1;
      tf2x32(k0, k1, e0, e0 + HALF_H, o0, o1);
      h_lds[rlo][jj]      = (sigmoidf_(xlo) > tf_uniform(o0)) ? (unsigned short)0x3F80 : (unsigned short)0;
      h_lds[16 + rlo][jj] = (sigmoidf_(xhi) > tf_uniform(o1)) ? (unsigned short)0x3F80 : (unsigned short)0;
    }
  }
}

// ---- fused CD-10 chain + free energy; 32 rows/block; wave w owns cols [512w,512w+512) ----
__global__ __launch_bounds__(512, 2)
void rbm_chain(const float* __restrict__ inputs, const float* __restrict__ vb,
               const float* __restrict__ hb,
               const unsigned short* __restrict__ w_hi, const unsigned short* __restrict__ w_lo,
               const unsigned short* __restrict__ wt_hi, const unsigned short* __restrict__ wt_lo,
               float* __restrict__ partial, TFKeys K) {
  __shared__ unsigned short v_lds[8][32][72];  // per-wave 64-col sub-chunk (+8 pad)
  __shared__ float Xp[32][64][8];              // per-wave X partials, w innermost
  __shared__ unsigned short h_lds[32][72];
  __shared__ float vb_lds[4096];
  __shared__ float hb_lds[64];
  __shared__ float red[8];

  const int tid = threadIdx.x;
  const int wv  = tid >> 6;    // wave 0..7
  const int l   = tid & 63;
  const int lg  = l >> 4;      // 0..3
  const int lr  = l & 15;
  const int b0  = blockIdx.x * 16;
  const int colbase = wv * 512;

  for (int u = tid; u < 1024; u += 512)
    ((float4*)vb_lds)[u] = ((const float4*)vb)[u];
  if (tid < 64) hb_lds[tid] = hb[tid];
  __syncthreads();

  float acc_fe = 0.0f;
  f32x4 accx[2][4];
  #pragma unroll
  for (int rt = 0; rt < 2; ++rt)
    #pragma unroll
    for (int ct = 0; ct < 4; ++ct) accx[rt][ct] = f32x4{0.f, 0.f, 0.f, 0.f};

  // ================= X0 = inputs @ w (per-wave K-slice) =====================
  #pragma unroll 1
  for (int sc = 0; sc < 8; ++sc) {
    const int base = colbase + sc * 64;
    // stage 32 rows x 64 cols of inputs -> bf16; accumulate -inputs.vb
    #pragma unroll
    for (int u = 0; u < 8; ++u) {
      int idx = u * 64 + l;            // 0..511
      int row = idx >> 4, f4 = idx & 15;
      int grow = (row < 16) ? (b0 + row) : (4096 + b0 + row - 16);
      float4 x = *(const float4*)(inputs + (size_t)grow * 4096 + base + f4 * 4);
      int cg = base + f4 * 4;
      acc_fe -= x.x * vb_lds[cg] + x.y * vb_lds[cg + 1]
              + x.z * vb_lds[cg + 2] + x.w * vb_lds[cg + 3];
      ushort4 h4;
      h4.x = f2bf(x.x); h4.y = f2bf(x.y); h4.z = f2bf(x.z); h4.w = f2bf(x.w);
      *(ushort4*)&v_lds[wv][row][f4 * 4] = h4;
    }
    // accumulate X0 partial over this sub-chunk (K = 64 -> 2 k-steps)
    #pragma unroll
    for (int ks = 0; ks < 2; ++ks) {
      const int kg = base + ks * 32;
      bf16x8 A0 = as8(*(const uint4*)&v_lds[wv][lr][ks * 32 + lg * 8]);
      bf16x8 A1 = as8(*(const uint4*)&v_lds[wv][16 + lr][ks * 32 + lg * 8]);
      #pragma unroll
      for (int ct = 0; ct < 4; ++ct) {
        size_t wo = (size_t)(ct * 16 + lr) * 4096 + kg + lg * 8;
        bf16x8 bh = as8(*(const uint4*)(wt_hi + wo));
        bf16x8 bl = as8(*(const uint4*)(wt_lo + wo));
        accx[0][ct] = __builtin_amdgcn_mfma_f32_16x16x32_bf16(A0, bh, accx[0][ct], 0, 0, 0);
        accx[0][ct] = __builtin_amdgcn_mfma_f32_16x16x32_bf16(A0, bl, accx[0][ct], 0, 0, 0);
        accx[1][ct] = __builtin_amdgcn_mfma_f32_16x16x32_bf16(A1, bh, accx[1][ct], 0, 0, 0);
        accx[1][ct] = __builtin_amdgcn_mfma_f32_16x16x32_bf16(A1, bl, accx[1][ct], 0, 0, 0);
      }
    }
  }
  #pragma unroll
  for (int rt = 0; rt < 2; ++rt)
    #pragma unroll
    for (int ct = 0; ct < 4; ++ct)
      #pragma unroll
      for (int q = 0; q < 4; ++q)
        Xp[rt * 16 + lg * 4 + q][ct * 16 + lr][wv] = accx[rt][ct][q];
  __syncthreads();
  h_tail<0>(wv, l, b0, K.kh0_0, K.kh0_1, acc_fe, Xp, hb_lds, h_lds);
  __syncthreads();

  // ======================= 10 Gibbs steps ===================================
  for (int step = 0; step < NSTEP; ++step) {
    const uint32_t kv0 = K.kv0[step], kv1 = K.kv1[step];
    const bool last = (step == NSTEP - 1);

    bf16x8 ha00 = as8(*(const uint4*)&h_lds[lr][lg * 8]);
    bf16x8 ha01 = as8(*(const uint4*)&h_lds[lr][32 + lg * 8]);
    bf16x8 ha10 = as8(*(const uint4*)&h_lds[16 + lr][lg * 8]);
    bf16x8 ha11 = as8(*(const uint4*)&h_lds[16 + lr][32 + lg * 8]);

    #pragma unroll
    for (int rt = 0; rt < 2; ++rt)
      #pragma unroll
      for (int ct = 0; ct < 4; ++ct) accx[rt][ct] = f32x4{0.f, 0.f, 0.f, 0.f};

    #pragma unroll 1
    for (int sc = 0; sc < 8; ++sc) {
      const int base = colbase + sc * 64;
      // ---- v-phase: 4 tiles of 16 cols; sample v into own v_lds region ----
      #pragma unroll
      for (int t = 0; t < 4; ++t) {
        const int ig = base + t * 16 + lr;
        const uint4* wh = (const uint4*)(w_hi + (size_t)ig * 64);
        const uint4* wl = (const uint4*)(w_lo + (size_t)ig * 64);
        bf16x8 bh0 = as8(wh[lg]);
        bf16x8 bh1 = as8(wh[4 + lg]);
        bf16x8 bl0 = as8(wl[lg]);
        bf16x8 bl1 = as8(wl[4 + lg]);
        f32x4 a0 = {0.f, 0.f, 0.f, 0.f}, a1 = {0.f, 0.f, 0.f, 0.f};
        a0 = __builtin_amdgcn_mfma_f32_16x16x32_bf16(ha00, bh0, a0, 0, 0, 0);
        a0 = __builtin_amdgcn_mfma_f32_16x16x32_bf16(ha01, bh1, a0, 0, 0, 0);
        a0 = __builtin_amdgcn_mfma_f32_16x16x32_bf16(ha00, bl0, a0, 0, 0, 0);
        a0 = __builtin_amdgcn_mfma_f32_16x16x32_bf16(ha01, bl1, a0, 0, 0, 0);
        a1 = __builtin_amdgcn_mfma_f32_16x16x32_bf16(ha10, bh0, a1, 0, 0, 0);
        a1 = __builtin_amdgcn_mfma_f32_16x16x32_bf16(ha11, bh1, a1, 0, 0, 0);
        a1 = __builtin_amdgcn_mfma_f32_16x16x32_bf16(ha10, bl0, a1, 0, 0, 0);
        a1 = __builtin_amdgcn_mfma_f32_16x16x32_bf16(ha11, bl1, a1, 0, 0, 0);
        const float vbv  = vb_lds[ig];
        const float vbva = last ? vbv : 0.0f;   // branchless last-step v.vb term
        #pragma unroll
        for (int q = 0; q < 4; ++q) {
          const int rit = lg * 4 + q;
          float x0 = a0[q] + vbv, x1 = a1[q] + vbv;
          uint32_t e0 = (uint32_t)(b0 + rit) * 4096u + (uint32_t)ig;
          uint32_t o0, o1;
          tf2x32(kv0, kv1, e0, e0 + HALF_V, o0, o1);
          bool s0 = sigmoidf_(x0) > tf_uniform(o0);
          bool s1 = sigmoidf_(x1) > tf_uniform(o1);
          v_lds[wv][rit][t * 16 + lr]      = s0 ? (unsigned short)0x3F80 : (unsigned short)0;
          v_lds[wv][16 + rit][t * 16 + lr] = s1 ? (unsigned short)0x3F80 : (unsigned short)0;
          acc_fe += (s0 ? vbva : 0.0f) + (s1 ? vbva : 0.0f);
        }
      }
      // ---- h-phase partial: X += Vchunk @ W over own K-slice ----
      #pragma unroll
      for (int ks = 0; ks < 2; ++ks) {
        const int kg = base + ks * 32;
        bf16x8 A0 = as8(*(const uint4*)&v_lds[wv][lr][ks * 32 + lg * 8]);
        bf16x8 A1 = as8(*(const uint4*)&v_lds[wv][16 + lr][ks * 32 + lg * 8]);
        #pragma unroll
        for (int ct = 0; ct < 4; ++ct) {
          size_t wo = (size_t)(ct * 16 + lr) * 4096 + kg + lg * 8;
          bf16x8 bh = as8(*(const uint4*)(wt_hi + wo));
          bf16x8 bl = as8(*(const uint4*)(wt_lo + wo));
          accx[0][ct] = __builtin_amdgcn_mfma_f32_16x16x32_bf16(A0, bh, accx[0][ct], 0, 0, 0);
          accx[0][ct] = __builtin_amdgcn_mfma_f32_16x16x32_bf16(A0, bl, accx[0][ct], 0, 0, 0);
          accx[1][ct] = __builtin_amdgcn_mfma_f32_16x16x32_bf16(A1, bh, accx[1][ct], 0, 0, 0);
          accx[1][ct] = __builtin_amdgcn_mfma_f32_16x16x32_bf16(A1, bl, accx[1][ct], 0, 0, 0);
        }
      }
    }

    #pragma unroll
    for (int rt = 0; rt < 2; ++rt)
      #pragma unroll
      for (int ct = 0; ct < 4; ++ct)
        #pragma unroll
        for (int q = 0; q < 4; ++q)
          Xp[rt * 16 + lg * 4 + q][ct * 16 + lr][wv] = accx[rt][ct][q];
    __syncthreads();
    if (last) h_tail<2>(wv, l, b0, 0u, 0u, acc_fe, Xp, hb_lds, h_lds);
    else      h_tail<1>(wv, l, b0, K.khs0[step], K.khs1[step], acc_fe, Xp, hb_lds, h_lds);
    __syncthreads();
  }

  // ---- block reduction ----
  float v = acc_fe;
  #pragma unroll
  for (int off = 32; off; off >>= 1) v += __shfl_down(v, off);
  if (l == 0) red[wv] = v;
  __syncthreads();
  if (tid == 0) {
    float s = 0.f;
    #pragma unroll
    for (int i = 0; i < 8; ++i) s += red[i];
    partial[blockIdx.x] = s;
  }
}

__global__ void finish_reduce(const float* __restrict__ partial, float* __restrict__ out) {
  __shared__ float r[4];
  float v = partial[threadIdx.x];   // 256 threads
  #pragma unroll
  for (int off = 32; off; off >>= 1) v += __shfl_down(v, off);
  if ((threadIdx.x & 63) == 0) r[threadIdx.x >> 6] = v;
  __syncthreads();
  if (threadIdx.x == 0) out[0] = r[0] + r[1] + r[2] + r[3];
}

extern "C" void kernel_launch(void* const* d_in, const int* in_sizes, int n_in,
                              void* d_out, int out_size, void* d_ws, size_t ws_size,
                              hipStream_t stream) {
  const float* inputs = (const float*)d_in[0];
  const float* w      = (const float*)d_in[1];
  const float* vb     = (const float*)d_in[2];
  const float* hb     = (const float*)d_in[3];
  float* out = (float*)d_out;

  unsigned short* w_hi  = (unsigned short*)d_ws;                          // 512 KB
  unsigned short* w_lo  = (unsigned short*)((char*)d_ws + (512u << 10));  // 512 KB
  unsigned short* wt_hi = (unsigned short*)((char*)d_ws + (1024u << 10)); // 512 KB
  unsigned short* wt_lo = (unsigned short*)((char*)d_ws + (1536u << 10)); // 512 KB
  float* partial        = (float*)((char*)d_ws + (2048u << 10));

  // ---- JAX threefry key schedule on host (pure arithmetic, capture-safe) ----
  TFKeys K;
  uint32_t kc0, kc1;
  tf2x32(0u, 42u, 0u, 0u, K.kh0_0, K.kh0_1);   // fold_in(key(42), 0)
  tf2x32(0u, 42u, 0u, 1u, kc0, kc1);           // fold_in(key(42), 1)
  // split(kchain, 10): counts = iota(20), cipher pairs (i, 10+i)
  uint32_t A[NSTEP], B[NSTEP], flat[2 * NSTEP];
  for (int i = 0; i < NSTEP; ++i) tf2x32(kc0, kc1, (uint32_t)i, (uint32_t)(NSTEP + i), A[i], B[i]);
  for (int i = 0; i < NSTEP; ++i) { flat[i] = A[i]; flat[NSTEP + i] = B[i]; }
  for (int t = 0; t < NSTEP; ++t) {
    uint32_t key0 = flat[2 * t], key1 = flat[2 * t + 1];
    // split(keys[t], 2): counts = iota(4), cipher pairs (0,2) and (1,3)
    uint32_t C0, D0, C1, D1;
    tf2x32(key0, key1, 0u, 2u, C0, D0);
    tf2x32(key0, key1, 1u, 3u, C1, D1);
    K.kv0[t] = C0; K.kv1[t] = C1;    // kv = first row of reshaped (2,2)
    K.khs0[t] = D0; K.khs1[t] = D1;  // kh = second row
  }

  prep_w<<<1024, 256, 0, stream>>>(w, w_hi, w_lo, wt_hi, wt_lo);
  rbm_chain<<<256, 512, 0, stream>>>(inputs, vb, hb, w_hi, w_lo, wt_hi, wt_lo, partial, K);
  finish_reduce<<<1, 256, 0, stream>>>(partial, out);
}